// Round 1
// baseline (1773.643 us; speedup 1.0000x reference)
//
#include <hip/hip_runtime.h>

// GraphConv: out = relu(segment_sum(e_w * e_p * x[j], i))
// B=256, N=64, C=128, E = 1,048,576, nodes = 16384.
// Inputs (setup_inputs order):
//   d_in[0] n_feats    (B*N*C,) f32   = 2,097,152
//   d_in[1] e_weights  (E,)     f32   = 1,048,576
//   d_in[2] e_params   (E*C,)   f32   = 134,217,728
//   d_in[3] node_i_ids (E,)     i32   (destination)
//   d_in[4] node_j_ids (E,)     i32   (source)
// Output: (B*N*C,) f32 = 2,097,152

#define CDIM 128
#define NEDGES 1048576

// One edge per 32 lanes; each lane handles 4 channels (float4).
// e_params read is fully coalesced: 32 lanes x 16B = 512B contiguous per edge.
__global__ __launch_bounds__(256) void edge_scatter_kernel(
    const float* __restrict__ n_feats,
    const float* __restrict__ e_weights,
    const float* __restrict__ e_params,
    const int* __restrict__ node_i,
    const int* __restrict__ node_j,
    float* __restrict__ out)
{
    const int tid = blockIdx.x * blockDim.x + threadIdx.x;
    const int e  = tid >> 5;            // edge index
    const int cg = (tid & 31) << 2;     // channel offset: 0,4,...,124
    if (e >= NEDGES) return;

    const float w  = e_weights[e];      // wave-uniform per 32-lane group (broadcast)
    const int dst  = node_i[e];
    const int src  = node_j[e];

    const float4 p = *reinterpret_cast<const float4*>(&e_params[(size_t)e * CDIM + cg]);
    const float4 x = *reinterpret_cast<const float4*>(&n_feats[(size_t)src * CDIM + cg]);

    float* o = &out[(size_t)dst * CDIM + cg];
    atomicAdd(o + 0, w * p.x * x.x);
    atomicAdd(o + 1, w * p.y * x.y);
    atomicAdd(o + 2, w * p.z * x.z);
    atomicAdd(o + 3, w * p.w * x.w);
}

__global__ __launch_bounds__(256) void relu_inplace_kernel(float* __restrict__ out, int n4)
{
    const int i = blockIdx.x * blockDim.x + threadIdx.x;
    if (i < n4) {
        float4 v = reinterpret_cast<float4*>(out)[i];
        v.x = fmaxf(v.x, 0.f);
        v.y = fmaxf(v.y, 0.f);
        v.z = fmaxf(v.z, 0.f);
        v.w = fmaxf(v.w, 0.f);
        reinterpret_cast<float4*>(out)[i] = v;
    }
}

extern "C" void kernel_launch(void* const* d_in, const int* in_sizes, int n_in,
                              void* d_out, int out_size, void* d_ws, size_t ws_size,
                              hipStream_t stream)
{
    const float* n_feats   = (const float*)d_in[0];
    const float* e_weights = (const float*)d_in[1];
    const float* e_params  = (const float*)d_in[2];
    const int*   node_i    = (const int*)d_in[3];
    const int*   node_j    = (const int*)d_in[4];
    float*       out       = (float*)d_out;

    // Zero the accumulator (d_out is poisoned; untouched rows must be 0).
    hipMemsetAsync(d_out, 0, (size_t)out_size * sizeof(float), stream);

    // E edges * 32 lanes/edge = 33,554,432 threads -> 131072 blocks of 256.
    const int total_threads = NEDGES * 32;
    const int blocks = total_threads / 256;
    edge_scatter_kernel<<<blocks, 256, 0, stream>>>(
        n_feats, e_weights, e_params, node_i, node_j, out);

    const int n4 = out_size / 4;
    relu_inplace_kernel<<<(n4 + 255) / 256, 256, 0, stream>>>(out, n4);
}

// Round 2
// 339.988 us; speedup vs baseline: 5.2168x; 5.2168x over previous
//
#include <hip/hip_runtime.h>

// GraphConv: out = relu(segment_sum(e_w * e_p * x[j], i))
// B=256, N=64, C=128, E = 1,048,576, nodes = 16384.
//
// Strategy: counting-sort edge ids by destination node on-device each call,
// then gather-reduce per destination (one wave per node) -> zero data atomics.
//
// Workspace layout (ints):
//   [0, NNODES)          counts      (histogram)
//   [NNODES, 2*NNODES)   offsets     (exclusive starts; after scatter pass
//                                     they hold bin ENDS; start of bin k is
//                                     offsets[k-1], start of bin 0 is 0)
//   [2*NNODES, +E)       sorted edge ids

#define CDIM   128
#define NEDGES 1048576
#define NNODES 16384

__global__ __launch_bounds__(256) void hist_kernel(
    const int* __restrict__ node_i, int* __restrict__ counts)
{
    const int e = blockIdx.x * blockDim.x + threadIdx.x;
    if (e < NEDGES) atomicAdd(&counts[node_i[e]], 1);
}

// Exclusive scan of 16384 counts with one 256-thread block (64 bins/thread).
__global__ __launch_bounds__(256) void scan_kernel(
    const int* __restrict__ counts, int* __restrict__ offsets)
{
    __shared__ int partials[256];
    const int tid  = threadIdx.x;
    const int base = tid * 64;
    int s = 0;
    #pragma unroll
    for (int k = 0; k < 64; ++k) s += counts[base + k];
    partials[tid] = s;
    __syncthreads();
    if (tid == 0) {
        int run = 0;
        for (int i = 0; i < 256; ++i) { int t = partials[i]; partials[i] = run; run += t; }
    }
    __syncthreads();
    int run = partials[tid];
    #pragma unroll
    for (int k = 0; k < 64; ++k) { offsets[base + k] = run; run += counts[base + k]; }
}

__global__ __launch_bounds__(256) void scatter_ids_kernel(
    const int* __restrict__ node_i, int* __restrict__ offsets,
    int* __restrict__ sorted_eid)
{
    const int e = blockIdx.x * blockDim.x + threadIdx.x;
    if (e < NEDGES) {
        const int pos = atomicAdd(&offsets[node_i[e]], 1);
        sorted_eid[pos] = e;
    }
}

// One 64-lane wave per destination node; lane handles 2 channels (float2).
// Per edge: e_params read is 64 lanes x 8B = 512B contiguous (coalesced);
// n_feats source row likewise 512B contiguous (L2/LLC-resident, 8 MB total).
__global__ __launch_bounds__(256) void gather_kernel(
    const float* __restrict__ n_feats,
    const float* __restrict__ e_weights,
    const float* __restrict__ e_params,
    const int* __restrict__ node_j,
    const int* __restrict__ offsets,   // post-scatter: offsets[k] == end of bin k
    const int* __restrict__ sorted_eid,
    float* __restrict__ out)
{
    const int node = blockIdx.x * 4 + (threadIdx.x >> 6);
    const int lane = threadIdx.x & 63;
    const int start = (node == 0) ? 0 : offsets[node - 1];
    const int end   = offsets[node];

    float2 acc = make_float2(0.f, 0.f);
    for (int t = start; t < end; ++t) {
        const int e   = sorted_eid[t];
        const float w = e_weights[e];
        const int src = node_j[e];
        const float2 p = *reinterpret_cast<const float2*>(
            &e_params[(size_t)e * CDIM + lane * 2]);
        const float2 x = *reinterpret_cast<const float2*>(
            &n_feats[(size_t)src * CDIM + lane * 2]);
        acc.x += w * p.x * x.x;
        acc.y += w * p.y * x.y;
    }
    float2 r;
    r.x = fmaxf(acc.x, 0.f);
    r.y = fmaxf(acc.y, 0.f);
    *reinterpret_cast<float2*>(&out[(size_t)node * CDIM + lane * 2]) = r;
}

// ---- fallback (atomic) path, used only if ws_size is too small ----
__global__ __launch_bounds__(256) void edge_scatter_kernel(
    const float* __restrict__ n_feats,
    const float* __restrict__ e_weights,
    const float* __restrict__ e_params,
    const int* __restrict__ node_i,
    const int* __restrict__ node_j,
    float* __restrict__ out)
{
    const int tid = blockIdx.x * blockDim.x + threadIdx.x;
    const int e  = tid >> 5;
    const int cg = (tid & 31) << 2;
    if (e >= NEDGES) return;
    const float w = e_weights[e];
    const int dst = node_i[e];
    const int src = node_j[e];
    const float4 p = *reinterpret_cast<const float4*>(&e_params[(size_t)e * CDIM + cg]);
    const float4 x = *reinterpret_cast<const float4*>(&n_feats[(size_t)src * CDIM + cg]);
    float* o = &out[(size_t)dst * CDIM + cg];
    atomicAdd(o + 0, w * p.x * x.x);
    atomicAdd(o + 1, w * p.y * x.y);
    atomicAdd(o + 2, w * p.z * x.z);
    atomicAdd(o + 3, w * p.w * x.w);
}

__global__ __launch_bounds__(256) void relu_inplace_kernel(float* __restrict__ out, int n4)
{
    const int i = blockIdx.x * blockDim.x + threadIdx.x;
    if (i < n4) {
        float4 v = reinterpret_cast<float4*>(out)[i];
        v.x = fmaxf(v.x, 0.f); v.y = fmaxf(v.y, 0.f);
        v.z = fmaxf(v.z, 0.f); v.w = fmaxf(v.w, 0.f);
        reinterpret_cast<float4*>(out)[i] = v;
    }
}

extern "C" void kernel_launch(void* const* d_in, const int* in_sizes, int n_in,
                              void* d_out, int out_size, void* d_ws, size_t ws_size,
                              hipStream_t stream)
{
    const float* n_feats   = (const float*)d_in[0];
    const float* e_weights = (const float*)d_in[1];
    const float* e_params  = (const float*)d_in[2];
    const int*   node_i    = (const int*)d_in[3];
    const int*   node_j    = (const int*)d_in[4];
    float*       out       = (float*)d_out;

    const size_t need_bytes = (size_t)(2 * NNODES + NEDGES) * sizeof(int);
    if (ws_size >= need_bytes) {
        int* counts     = (int*)d_ws;
        int* offsets    = counts + NNODES;
        int* sorted_eid = offsets + NNODES;

        hipMemsetAsync(counts, 0, (size_t)NNODES * sizeof(int), stream);

        const int eblocks = NEDGES / 256;
        hist_kernel<<<eblocks, 256, 0, stream>>>(node_i, counts);
        scan_kernel<<<1, 256, 0, stream>>>(counts, offsets);
        scatter_ids_kernel<<<eblocks, 256, 0, stream>>>(node_i, offsets, sorted_eid);

        // 4 waves/block, one node per wave. All nodes written (degree-0 -> 0).
        gather_kernel<<<NNODES / 4, 256, 0, stream>>>(
            n_feats, e_weights, e_params, node_j, offsets, sorted_eid, out);
    } else {
        hipMemsetAsync(d_out, 0, (size_t)out_size * sizeof(float), stream);
        const int blocks = (NEDGES * 32) / 256;
        edge_scatter_kernel<<<blocks, 256, 0, stream>>>(
            n_feats, e_weights, e_params, node_i, node_j, out);
        const int n4 = out_size / 4;
        relu_inplace_kernel<<<(n4 + 255) / 256, 256, 0, stream>>>(out, n4);
    }
}

// Round 3
// 283.200 us; speedup vs baseline: 6.2629x; 1.2005x over previous
//
#include <hip/hip_runtime.h>

// GraphConv: out = relu(segment_sum(e_w * e_p * x[j], i))
// B=256, N=64, C=128, E = 1,048,576, nodes = 16384.
//
// Counting-sort edges by destination, then gather-reduce one wave per node.
// Gather v2: batch-load 64 edge ids + their (w, src) per chunk, broadcast via
// shuffle -> inner loop has no serial dependent-load chain; e_params row loads
// of successive edges are independent and pipeline at HBM BW.
//
// Workspace (ints):
//   [0, NNODES)          counts
//   [NNODES, 2*NNODES)   offsets  (after scatter: offsets[k] == end of bin k)
//   [2*NNODES, +E)       sorted edge ids

#define CDIM   128
#define NEDGES 1048576
#define NNODES 16384

__global__ __launch_bounds__(256) void hist_kernel(
    const int* __restrict__ node_i, int* __restrict__ counts)
{
    const int e = blockIdx.x * blockDim.x + threadIdx.x;
    if (e < NEDGES) atomicAdd(&counts[node_i[e]], 1);
}

// Exclusive scan of 16384 counts, one 256-thread block (64 bins/thread).
__global__ __launch_bounds__(256) void scan_kernel(
    const int* __restrict__ counts, int* __restrict__ offsets)
{
    __shared__ int partials[256];
    const int tid  = threadIdx.x;
    const int base = tid * 64;
    int s = 0;
    #pragma unroll
    for (int k = 0; k < 64; ++k) s += counts[base + k];
    partials[tid] = s;
    __syncthreads();
    if (tid == 0) {
        int run = 0;
        for (int i = 0; i < 256; ++i) { int t = partials[i]; partials[i] = run; run += t; }
    }
    __syncthreads();
    int run = partials[tid];
    #pragma unroll
    for (int k = 0; k < 64; ++k) { offsets[base + k] = run; run += counts[base + k]; }
}

__global__ __launch_bounds__(256) void scatter_ids_kernel(
    const int* __restrict__ node_i, int* __restrict__ offsets,
    int* __restrict__ sorted_eid)
{
    const int e = blockIdx.x * blockDim.x + threadIdx.x;
    if (e < NEDGES) {
        const int pos = atomicAdd(&offsets[node_i[e]], 1);
        sorted_eid[pos] = e;
    }
}

// One 64-lane wave per destination node; lane covers 2 channels (float2).
// Chunked: 64 edges' (eid, w, src) loaded batch-parallel across lanes,
// broadcast per-edge with __shfl (uniform index -> v_readlane).
__global__ __launch_bounds__(256) void gather_kernel(
    const float* __restrict__ n_feats,
    const float* __restrict__ e_weights,
    const float* __restrict__ e_params,
    const int* __restrict__ node_j,
    const int* __restrict__ offsets,
    const int* __restrict__ sorted_eid,
    float* __restrict__ out)
{
    const int node = blockIdx.x * 4 + (threadIdx.x >> 6);
    const int lane = threadIdx.x & 63;
    const int start = (node == 0) ? 0 : offsets[node - 1];
    const int end   = offsets[node];

    float accx = 0.f, accy = 0.f;

    for (int chunk = start; chunk < end; chunk += 64) {
        // Batch load this chunk's edge records across lanes (clamped, no branch).
        int t = chunk + lane;
        if (t >= end) t = end - 1;          // end > start inside loop
        const int   eid = sorted_eid[t];
        const float w   = e_weights[eid];
        const int   src = node_j[eid];

        const int m = (end - chunk < 64) ? (end - chunk) : 64;
        #pragma unroll 4
        for (int k = 0; k < m; ++k) {
            const int   e_k = __shfl(eid, k, 64);
            const float w_k = __shfl(w,   k, 64);
            const int   s_k = __shfl(src, k, 64);
            const float2 p = *reinterpret_cast<const float2*>(
                &e_params[(size_t)e_k * CDIM + lane * 2]);
            const float2 x = *reinterpret_cast<const float2*>(
                &n_feats[(size_t)s_k * CDIM + lane * 2]);
            accx += w_k * p.x * x.x;
            accy += w_k * p.y * x.y;
        }
    }

    float2 r;
    r.x = fmaxf(accx, 0.f);
    r.y = fmaxf(accy, 0.f);
    *reinterpret_cast<float2*>(&out[(size_t)node * CDIM + lane * 2]) = r;
}

extern "C" void kernel_launch(void* const* d_in, const int* in_sizes, int n_in,
                              void* d_out, int out_size, void* d_ws, size_t ws_size,
                              hipStream_t stream)
{
    const float* n_feats   = (const float*)d_in[0];
    const float* e_weights = (const float*)d_in[1];
    const float* e_params  = (const float*)d_in[2];
    const int*   node_i    = (const int*)d_in[3];
    const int*   node_j    = (const int*)d_in[4];
    float*       out       = (float*)d_out;
    (void)ws_size; (void)n_in; (void)in_sizes;

    int* counts     = (int*)d_ws;
    int* offsets    = counts + NNODES;
    int* sorted_eid = offsets + NNODES;

    hipMemsetAsync(counts, 0, (size_t)NNODES * sizeof(int), stream);

    const int eblocks = NEDGES / 256;
    hist_kernel<<<eblocks, 256, 0, stream>>>(node_i, counts);
    scan_kernel<<<1, 256, 0, stream>>>(counts, offsets);
    scatter_ids_kernel<<<eblocks, 256, 0, stream>>>(node_i, offsets, sorted_eid);

    gather_kernel<<<NNODES / 4, 256, 0, stream>>>(
        n_feats, e_weights, e_params, node_j, offsets, sorted_eid, out);
    (void)out_size;
}

// Round 5
// 252.908 us; speedup vs baseline: 7.0130x; 1.1198x over previous
//
#include <hip/hip_runtime.h>

// GraphConv: out = relu(segment_sum(e_w * e_p * x[j], i))
// B=256, N=64, C=128, E = 1,048,576, nodes = 16384.
//
// Counting-sort edges by destination into packed 16B records {eid, src, w},
// then gather-reduce: one wave per node, 2 edges in parallel per wave
// (32 lanes x float4 each), broadcasts via __shfl of the batch-loaded records.
//
// Workspace (from d_ws):
//   [0, 64KB)        counts   (16384 ints)
//   [64KB, 128KB)    offsets  (after scatter: offsets[k] == end of bin k)
//   [128KB, +16MB)   recs     (E x int4 {eid, src, w_bits, 0})

#define CDIM   128
#define NEDGES 1048576
#define NNODES 16384

// Native vector type for nontemporal builtins (HIP_vector_type is rejected).
typedef float f32x4 __attribute__((ext_vector_type(4)));

__global__ __launch_bounds__(256) void hist_kernel(
    const int* __restrict__ node_i, int* __restrict__ counts)
{
    const int e = blockIdx.x * blockDim.x + threadIdx.x;
    if (e < NEDGES) atomicAdd(&counts[node_i[e]], 1);
}

// Exclusive scan of 16384 counts, one 256-thread block (64 bins/thread).
__global__ __launch_bounds__(256) void scan_kernel(
    const int* __restrict__ counts, int* __restrict__ offsets)
{
    __shared__ int partials[256];
    const int tid  = threadIdx.x;
    const int base = tid * 64;
    int s = 0;
    #pragma unroll
    for (int k = 0; k < 64; ++k) s += counts[base + k];
    partials[tid] = s;
    __syncthreads();
    if (tid == 0) {
        int run = 0;
        for (int i = 0; i < 256; ++i) { int t = partials[i]; partials[i] = run; run += t; }
    }
    __syncthreads();
    int run = partials[tid];
    #pragma unroll
    for (int k = 0; k < 64; ++k) { offsets[base + k] = run; run += counts[base + k]; }
}

// Scatter packed records so the gather never does random 4B fetches.
__global__ __launch_bounds__(256) void scatter_rec_kernel(
    const int* __restrict__ node_i, const int* __restrict__ node_j,
    const float* __restrict__ e_weights,
    int* __restrict__ offsets, int4* __restrict__ recs)
{
    const int e = blockIdx.x * blockDim.x + threadIdx.x;
    if (e < NEDGES) {
        const int pos = atomicAdd(&offsets[node_i[e]], 1);
        int4 r;
        r.x = e;
        r.y = node_j[e];
        r.z = __float_as_int(e_weights[e]);
        r.w = 0;
        recs[pos] = r;
    }
}

// One 64-lane wave per node. Two edges in flight per iteration:
// half 0 (lanes 0-31) takes even chunk slots, half 1 odd slots.
// Each half covers all 128 channels with float4 per lane (16B).
__global__ __launch_bounds__(256) void gather_kernel(
    const float* __restrict__ n_feats,
    const float* __restrict__ e_params,
    const int* __restrict__ offsets,
    const int4* __restrict__ recs,
    float* __restrict__ out)
{
    const int node  = blockIdx.x * 4 + (threadIdx.x >> 6);
    const int lane  = threadIdx.x & 63;
    const int half  = lane >> 5;
    const int qlane = lane & 31;
    const int start = (node == 0) ? 0 : offsets[node - 1];
    const int end   = offsets[node];

    float4 acc = make_float4(0.f, 0.f, 0.f, 0.f);

    for (int chunk = start; chunk < end; chunk += 64) {
        int t = chunk + lane;
        if (t >= end) t = end - 1;          // end > start inside loop
        const int4 rec = recs[t];           // 64 x 16B coalesced batch
        const int m = (end - chunk < 64) ? (end - chunk) : 64;

        #pragma unroll 4
        for (int k = 0; k < m; k += 2) {
            int slot = k + half;
            const bool valid = slot < m;
            if (!valid) slot = m - 1;       // address-safe clamp
            const int   e_k = __shfl(rec.x, slot, 64);
            const int   s_k = __shfl(rec.y, slot, 64);
            float       w_k = __int_as_float(__shfl(rec.z, slot, 64));
            if (!valid) w_k = 0.f;          // zero contribution for pad slot

            const f32x4 p = __builtin_nontemporal_load(
                reinterpret_cast<const f32x4*>(&e_params[(size_t)e_k * CDIM + qlane * 4]));
            const f32x4 x = *reinterpret_cast<const f32x4*>(
                &n_feats[(size_t)s_k * CDIM + qlane * 4]);

            acc.x += w_k * p.x * x.x;
            acc.y += w_k * p.y * x.y;
            acc.z += w_k * p.z * x.z;
            acc.w += w_k * p.w * x.w;
        }
    }

    // Combine the two half-wave partials (same channels in both halves).
    acc.x += __shfl_xor(acc.x, 32, 64);
    acc.y += __shfl_xor(acc.y, 32, 64);
    acc.z += __shfl_xor(acc.z, 32, 64);
    acc.w += __shfl_xor(acc.w, 32, 64);

    if (half == 0) {
        f32x4 r;
        r.x = fmaxf(acc.x, 0.f);
        r.y = fmaxf(acc.y, 0.f);
        r.z = fmaxf(acc.z, 0.f);
        r.w = fmaxf(acc.w, 0.f);
        __builtin_nontemporal_store(
            r, reinterpret_cast<f32x4*>(&out[(size_t)node * CDIM + qlane * 4]));
    }
}

extern "C" void kernel_launch(void* const* d_in, const int* in_sizes, int n_in,
                              void* d_out, int out_size, void* d_ws, size_t ws_size,
                              hipStream_t stream)
{
    const float* n_feats   = (const float*)d_in[0];
    const float* e_weights = (const float*)d_in[1];
    const float* e_params  = (const float*)d_in[2];
    const int*   node_i    = (const int*)d_in[3];
    const int*   node_j    = (const int*)d_in[4];
    float*       out       = (float*)d_out;
    (void)ws_size; (void)n_in; (void)in_sizes; (void)out_size;

    int*  counts  = (int*)d_ws;
    int*  offsets = counts + NNODES;
    int4* recs    = (int4*)((char*)d_ws + 2 * NNODES * sizeof(int));

    (void)hipMemsetAsync(counts, 0, (size_t)NNODES * sizeof(int), stream);

    const int eblocks = NEDGES / 256;
    hist_kernel<<<eblocks, 256, 0, stream>>>(node_i, counts);
    scan_kernel<<<1, 256, 0, stream>>>(counts, offsets);
    scatter_rec_kernel<<<eblocks, 256, 0, stream>>>(
        node_i, node_j, e_weights, offsets, recs);

    gather_kernel<<<NNODES / 4, 256, 0, stream>>>(
        n_feats, e_params, offsets, recs, out);
}